// Round 6
// baseline (196.119 us; speedup 1.0000x reference)
//
#include <hip/hip_runtime.h>
#include <stdint.h>

// Problem dims (fixed): B=2, S=2048, D=1024, H=16, d_head=64
#define SEQ 2048
#define A_SIZE 4194304   // 2*2048*1024 floats (output 'a'), present follows

typedef short short8 __attribute__((ext_vector_type(8)));
typedef float f32x4 __attribute__((ext_vector_type(4)));

#define AS1 __attribute__((address_space(1)))
#define AS3 __attribute__((address_space(3)))

static __device__ __forceinline__ void async16(const void* g, void* l) {
  __builtin_amdgcn_global_load_lds((const AS1 uint32_t*)g, (AS3 uint32_t*)l, 16, 0, 0);
}

static __device__ __forceinline__ unsigned short f2bf(float f) {
  union { float f; uint32_t u; } v; v.f = f;
  uint32_t u = v.u;
  return (unsigned short)((u + 0x7FFFu + ((u >> 16) & 1u)) >> 16);
}

static __device__ __forceinline__ uint32_t fbits(float f) {
  union { float f; uint32_t u; } v; v.f = f;
  return v.u;
}

// pack two floats to two truncated bf16 in one u32: low=p0, high=p1
static __device__ __forceinline__ uint32_t pack_bf2(float p0, float p1) {
  return __builtin_amdgcn_perm(fbits(p1), fbits(p0), 0x07060302u);
}

// ---------------- convert x -> bf16 (straight) ----------------
__global__ void k_cvt(const float* __restrict__ in, unsigned short* __restrict__ out, int n4) {
  int i = blockIdx.x * blockDim.x + threadIdx.x;
  if (i >= n4) return;
  float4 f = ((const float4*)in)[i];
  ushort4 o;
  o.x = f2bf(f.x); o.y = f2bf(f.y); o.z = f2bf(f.z); o.w = f2bf(f.w);
  ((ushort4*)out)[i] = o;
}

// ------- convert + transpose: in [R][C] f32 -> out [C][R] bf16 -------
__global__ void k_tcvt(const float* __restrict__ in, unsigned short* __restrict__ out,
                       int R, int C) {
  __shared__ unsigned short tile[64][65];
  int c0 = blockIdx.x * 64, r0 = blockIdx.y * 64;
  int tid = threadIdx.x;
  #pragma unroll
  for (int it = 0; it < 16; ++it) {
    int idx = it * 256 + tid;
    int r = idx >> 6, c = idx & 63;
    tile[r][c] = f2bf(in[(size_t)(r0 + r) * C + c0 + c]);
  }
  __syncthreads();
  #pragma unroll
  for (int it = 0; it < 16; ++it) {
    int idx = it * 256 + tid;
    int r = idx >> 6, c = idx & 63;
    out[(size_t)(c0 + r) * R + r0 + c] = tile[c][r];
  }
}

// ---------------- QKV GEMM: C[4096,3072] = A[4096,1024] * BT[3072,1024]^T + bias ----
__global__ __launch_bounds__(256) void k_gemm_qkv(
    const unsigned short* __restrict__ A,
    const unsigned short* __restrict__ BT,
    const float* __restrict__ bias,
    float* __restrict__ outp,          // d_out base; present at +A_SIZE
    unsigned short* __restrict__ q_ws,
    unsigned short* __restrict__ k_ws,
    unsigned short* __restrict__ vT_ws) {
  const int K = 1024;
  __shared__ unsigned short Asm[128 * 32];
  __shared__ unsigned short Bsm[128 * 32];
  int tid = threadIdx.x;
  int lane = tid & 63, w = tid >> 6;
  int g = lane >> 4, qi = lane & 15;
  int wr = w >> 1, wc = w & 1;
  int bm = blockIdx.x & 31, bn = blockIdx.x >> 5;
  const unsigned short* Ag = A + (size_t)bm * 128 * K;
  const unsigned short* Bg = BT + (size_t)bn * 128 * K;
  f32x4 acc[4][4] = {};
  for (int kt = 0; kt < K; kt += 32) {
    #pragma unroll
    for (int i = 0; i < 2; ++i) {
      int j = i * 256 + tid;
      async16(Ag + (size_t)(j >> 2) * K + kt + (j & 3) * 8,
              (char*)Asm + (i * 256 + w * 64) * 16);
      async16(Bg + (size_t)(j >> 2) * K + kt + (j & 3) * 8,
              (char*)Bsm + (i * 256 + w * 64) * 16);
    }
    __syncthreads();
    short8 af[4], bf[4];
    #pragma unroll
    for (int mi = 0; mi < 4; ++mi)
      af[mi] = *(const short8*)&Asm[(wr * 64 + mi * 16 + qi) * 32 + g * 8];
    #pragma unroll
    for (int ni = 0; ni < 4; ++ni)
      bf[ni] = *(const short8*)&Bsm[(wc * 64 + ni * 16 + qi) * 32 + g * 8];
    #pragma unroll
    for (int mi = 0; mi < 4; ++mi)
      #pragma unroll
      for (int ni = 0; ni < 4; ++ni)
        acc[mi][ni] = __builtin_amdgcn_mfma_f32_16x16x32_bf16(af[mi], bf[ni], acc[mi][ni], 0, 0, 0);
    __syncthreads();
  }
  // Epilogue: scatter to q/k (bf16, [B,H,S,d]), v transposed ([B,H,d,S]), present (fp32).
  int m_base = bm * 128 + wr * 64;
  int n_base = bn * 128 + wc * 64;
  #pragma unroll
  for (int ni = 0; ni < 4; ++ni) {
    int n = n_base + ni * 16 + qi;
    float bv = bias[n];
    int which = n >> 10;
    int h = (n & 1023) >> 6, d = n & 63;
    #pragma unroll
    for (int mi = 0; mi < 4; ++mi) {
      #pragma unroll
      for (int r = 0; r < 4; ++r) {
        int m = m_base + mi * 16 + g * 4 + r;
        float val = acc[mi][ni][r] + bv;
        int b = m >> 11, s = m & 2047;
        if (which == 0) {
          q_ws[(((size_t)(b * 16 + h)) * SEQ + s) * 64 + d] = f2bf(val);
        } else if (which == 1) {
          outp[A_SIZE + (((size_t)(b * 32 + h)) * SEQ + s) * 64 + d] = val;      // present[b][0][h]
          k_ws[(((size_t)(b * 16 + h)) * SEQ + s) * 64 + d] = f2bf(val);
        } else {
          outp[A_SIZE + (((size_t)(b * 32 + 16 + h)) * SEQ + s) * 64 + d] = val; // present[b][1][h]
          vT_ws[(((size_t)(b * 16 + h)) * 64 + d) * SEQ + s] = f2bf(val);        // V^T
        }
      }
    }
  }
}

// ---------------- proj GEMM: out[4096,1024] = A[4096,1024] * BT[1024,1024]^T + bias ----
__global__ __launch_bounds__(256) void k_gemm_proj(
    const unsigned short* __restrict__ A,
    const unsigned short* __restrict__ BT,
    const float* __restrict__ bias,
    float* __restrict__ outp) {
  const int K = 1024;
  __shared__ unsigned short Asm[128 * 32];
  __shared__ unsigned short Bsm[128 * 32];
  int tid = threadIdx.x;
  int lane = tid & 63, w = tid >> 6;
  int g = lane >> 4, qi = lane & 15;
  int wr = w >> 1, wc = w & 1;
  int bm = blockIdx.x & 31, bn = blockIdx.x >> 5;
  const unsigned short* Ag = A + (size_t)bm * 128 * K;
  const unsigned short* Bg = BT + (size_t)bn * 128 * K;
  f32x4 acc[4][4] = {};
  for (int kt = 0; kt < K; kt += 32) {
    #pragma unroll
    for (int i = 0; i < 2; ++i) {
      int j = i * 256 + tid;
      async16(Ag + (size_t)(j >> 2) * K + kt + (j & 3) * 8,
              (char*)Asm + (i * 256 + w * 64) * 16);
      async16(Bg + (size_t)(j >> 2) * K + kt + (j & 3) * 8,
              (char*)Bsm + (i * 256 + w * 64) * 16);
    }
    __syncthreads();
    short8 af[4], bf[4];
    #pragma unroll
    for (int mi = 0; mi < 4; ++mi)
      af[mi] = *(const short8*)&Asm[(wr * 64 + mi * 16 + qi) * 32 + g * 8];
    #pragma unroll
    for (int ni = 0; ni < 4; ++ni)
      bf[ni] = *(const short8*)&Bsm[(wc * 64 + ni * 16 + qi) * 32 + g * 8];
    #pragma unroll
    for (int mi = 0; mi < 4; ++mi)
      #pragma unroll
      for (int ni = 0; ni < 4; ++ni)
        acc[mi][ni] = __builtin_amdgcn_mfma_f32_16x16x32_bf16(af[mi], bf[ni], acc[mi][ni], 0, 0, 0);
    __syncthreads();
  }
  int m_base = bm * 128 + wr * 64;
  int n_base = bn * 128 + wc * 64;
  #pragma unroll
  for (int ni = 0; ni < 4; ++ni) {
    int n = n_base + ni * 16 + qi;
    float bv = bias[n];
    #pragma unroll
    for (int mi = 0; mi < 4; ++mi)
      #pragma unroll
      for (int r = 0; r < 4; ++r) {
        int m = m_base + mi * 16 + g * 4 + r;
        outp[(size_t)m * 1024 + n] = acc[mi][ni][r] + bv;
      }
  }
}

// ---------------- flash attention (causal), zero-LDS, register-resident P ------------
// Key trick: permute the K-fragment ROW index per MFMA so QK^T's C-layout lands
// scores for lane (g,qi) at keys g*8..g*8+7 — exactly the PV B-fragment layout.
// P never leaves registers: no LDS, no cross-lane ops in the loop.
// XCD swizzle: xcd = bid&7 serves heads {4*xcd..4*xcd+3} -> 2MB K/V per XCD L2.
#define CSC 0.18033688f   /* 0.125 * log2(e) */
__global__ __launch_bounds__(512, 4) void k_attn(
    const unsigned short* __restrict__ q_ws,
    const unsigned short* __restrict__ k_ws,
    const unsigned short* __restrict__ vT_ws,
    unsigned short* __restrict__ a_out) {
  int bid = blockIdx.x;
  int xcd = bid & 7;
  int j = bid >> 3;                  // 0..63
  int bh = xcd * 4 + (j & 3);        // 4 heads per XCD -> K/V L2-resident
  int pairidx = j >> 2;              // 0..15
  int tid = threadIdx.x, lane = tid & 63, w = tid >> 6;
  int g = lane >> 4, qi = lane & 15;
  int tilesel = w >> 2, wl = w & 3;
  int q0 = (tilesel ? pairidx : (31 - pairidx)) * 64;
  int qw = q0 + wl * 16;
  int qrow = qw + qi;
  const unsigned short* Qb = q_ws + (size_t)bh * SEQ * 64;
  const unsigned short* Kb = k_ws + (size_t)bh * SEQ * 64;
  const unsigned short* Vb = vT_ws + (size_t)bh * 64 * SEQ;

  // permuted A-row index: row m of the K-fragment tile maps to key (m>>2)*8+(m&3)
  int pr = ((qi >> 2) * 8) + (qi & 3);

  short8 qf0 = *(const short8*)&Qb[(size_t)qrow * 64 + g * 8];
  short8 qf1 = *(const short8*)&Qb[(size_t)qrow * 64 + g * 8 + 32];

  f32x4 oacc[4] = {};
  float m2 = -1.0e30f, l_run = 0.f;   // per-lane partial sum over this lane's keys
  f32x4 z = {};

  // ---- unmasked 64-key body ----
  int nfull = qw >> 6;
  for (int kb = 0; kb < nfull; ++kb) {
    int k0 = kb * 64;
    // K rows permuted: st covers keys (st>>1)*32 + (st&1)*4 + {pr}
    short8 kf[4][2];
    #pragma unroll
    for (int st = 0; st < 4; ++st) {
      int row = k0 + (st >> 1) * 32 + (st & 1) * 4 + pr;
      kf[st][0] = *(const short8*)&Kb[(size_t)row * 64 + g * 8];
      kf[st][1] = *(const short8*)&Kb[(size_t)row * 64 + g * 8 + 32];
    }
    short8 vf0[4], vf1[4];
    #pragma unroll
    for (int dt = 0; dt < 4; ++dt) {
      vf0[dt] = *(const short8*)&Vb[(size_t)(dt * 16 + qi) * SEQ + k0 + g * 8];
      vf1[dt] = *(const short8*)&Vb[(size_t)(dt * 16 + qi) * SEQ + k0 + 32 + g * 8];
    }
    f32x4 sa[4];
    #pragma unroll
    for (int st = 0; st < 4; ++st) {
      sa[st] = __builtin_amdgcn_mfma_f32_16x16x32_bf16(kf[st][0], qf0, z, 0, 0, 0);
      sa[st] = __builtin_amdgcn_mfma_f32_16x16x32_bf16(kf[st][1], qf1, sa[st], 0, 0, 0);
    }
    // lane (g,qi) now holds S[q=qw+qi][keys k0 + {g*8..g*8+3}(st0), {g*8+4..7}(st1),
    //                                     {32+g*8..+3}(st2), {32+g*8+4..7}(st3)]
    float tm = -1.0e30f;
    #pragma unroll
    for (int st = 0; st < 4; ++st)
      #pragma unroll
      for (int r = 0; r < 4; ++r) {
        sa[st][r] *= CSC;
        tm = fmaxf(tm, sa[st][r]);
      }
    if (!__all(tm - m2 <= 4.0f)) {      // defer-max (partial-max bound suffices)
      tm = fmaxf(tm, __shfl_xor(tm, 16, 64));
      tm = fmaxf(tm, __shfl_xor(tm, 32, 64));
      float mn = fmaxf(m2, tm);
      float alpha = exp2f(m2 - mn);
      l_run *= alpha;
      #pragma unroll
      for (int dt = 0; dt < 4; ++dt)
        #pragma unroll
        for (int r = 0; r < 4; ++r) oacc[dt][r] *= alpha;
      m2 = mn;
    }
    float ps = 0.f;
    union { uint32_t u[4]; short8 s; } pb0, pb1;
    #pragma unroll
    for (int st = 0; st < 4; ++st) {
      float p0 = exp2f(sa[st][0] - m2);
      float p1 = exp2f(sa[st][1] - m2);
      float p2 = exp2f(sa[st][2] - m2);
      float p3 = exp2f(sa[st][3] - m2);
      ps += (p0 + p1) + (p2 + p3);
      uint32_t lo = pack_bf2(p0, p1), hi = pack_bf2(p2, p3);
      if (st < 2) { pb0.u[st * 2] = lo; pb0.u[st * 2 + 1] = hi; }
      else        { pb1.u[(st - 2) * 2] = lo; pb1.u[(st - 2) * 2 + 1] = hi; }
    }
    l_run += ps;
    #pragma unroll
    for (int dt = 0; dt < 4; ++dt) {
      oacc[dt] = __builtin_amdgcn_mfma_f32_16x16x32_bf16(vf0[dt], pb0.s, oacc[dt], 0, 0, 0);
      oacc[dt] = __builtin_amdgcn_mfma_f32_16x16x32_bf16(vf1[dt], pb1.s, oacc[dt], 0, 0, 0);
    }
  }

  // ---- masked 32-key tail (1 or 2 iterations) ----
  int k0t = qw & ~63;
  int ntail = ((qw & 63) + 16 + 31) >> 5;
  for (int tt = 0; tt < ntail; ++tt) {
    int k0 = k0t + tt * 32;
    short8 kf[2][2];
    #pragma unroll
    for (int st = 0; st < 2; ++st) {
      int row = k0 + st * 4 + pr;
      kf[st][0] = *(const short8*)&Kb[(size_t)row * 64 + g * 8];
      kf[st][1] = *(const short8*)&Kb[(size_t)row * 64 + g * 8 + 32];
    }
    short8 vf[4];
    #pragma unroll
    for (int dt = 0; dt < 4; ++dt)
      vf[dt] = *(const short8*)&Vb[(size_t)(dt * 16 + qi) * SEQ + k0 + g * 8];
    f32x4 sa[2];
    #pragma unroll
    for (int st = 0; st < 2; ++st) {
      sa[st] = __builtin_amdgcn_mfma_f32_16x16x32_bf16(kf[st][0], qf0, z, 0, 0, 0);
      sa[st] = __builtin_amdgcn_mfma_f32_16x16x32_bf16(kf[st][1], qf1, sa[st], 0, 0, 0);
    }
    float tm = -1.0e30f;
    #pragma unroll
    for (int st = 0; st < 2; ++st)
      #pragma unroll
      for (int r = 0; r < 4; ++r) {
        int key = k0 + g * 8 + st * 4 + r;
        float v = (key <= qrow) ? sa[st][r] * CSC : -1.0e30f;
        sa[st][r] = v;
        tm = fmaxf(tm, v);
      }
    if (!__all(tm - m2 <= 4.0f)) {
      tm = fmaxf(tm, __shfl_xor(tm, 16, 64));
      tm = fmaxf(tm, __shfl_xor(tm, 32, 64));
      float mn = fmaxf(m2, tm);
      float alpha = exp2f(m2 - mn);
      l_run *= alpha;
      #pragma unroll
      for (int dt = 0; dt < 4; ++dt)
        #pragma unroll
        for (int r = 0; r < 4; ++r) oacc[dt][r] *= alpha;
      m2 = mn;
    }
    float ps = 0.f;
    union { uint32_t u[4]; short8 s; } pb;
    #pragma unroll
    for (int st = 0; st < 2; ++st) {
      float p0 = exp2f(sa[st][0] - m2);
      float p1 = exp2f(sa[st][1] - m2);
      float p2 = exp2f(sa[st][2] - m2);
      float p3 = exp2f(sa[st][3] - m2);
      ps += (p0 + p1) + (p2 + p3);
      pb.u[st * 2] = pack_bf2(p0, p1);
      pb.u[st * 2 + 1] = pack_bf2(p2, p3);
    }
    l_run += ps;
    #pragma unroll
    for (int dt = 0; dt < 4; ++dt)
      oacc[dt] = __builtin_amdgcn_mfma_f32_16x16x32_bf16(vf[dt], pb.s, oacc[dt], 0, 0, 0);
  }

  // one-time l reduce across the 4 lane-groups of each q-row
  l_run += __shfl_xor(l_run, 16, 64);
  l_run += __shfl_xor(l_run, 32, 64);
  float inv = 1.0f / l_run;
  int b = bh >> 4, h = bh & 15;
  size_t rowbase = ((size_t)(b * SEQ + qw + qi)) * 1024 + h * 64;
  #pragma unroll
  for (int dt = 0; dt < 4; ++dt) {
    ushort4 o;
    o.x = f2bf(oacc[dt][0] * inv);
    o.y = f2bf(oacc[dt][1] * inv);
    o.z = f2bf(oacc[dt][2] * inv);
    o.w = f2bf(oacc[dt][3] * inv);
    *(ushort4*)&a_out[rowbase + dt * 16 + g * 4] = o;
  }
}

// ---------------- launch ----------------
extern "C" void kernel_launch(void* const* d_in, const int* in_sizes, int n_in,
                              void* d_out, int out_size, void* d_ws, size_t ws_size,
                              hipStream_t stream) {
  const float* x      = (const float*)d_in[0];
  const float* w_attn = (const float*)d_in[1];
  const float* b_attn = (const float*)d_in[2];
  const float* w_proj = (const float*)d_in[3];
  const float* b_proj = (const float*)d_in[4];
  float* out = (float*)d_out;
  char* ws = (char*)d_ws;
  // ws layout (48 MB total)
  unsigned short* x_bf  = (unsigned short*)(ws);               //  8 MB
  unsigned short* waT   = (unsigned short*)(ws + 8388608);     //  6 MB
  unsigned short* wpT   = (unsigned short*)(ws + 14680064);    //  2 MB
  unsigned short* q_ws  = (unsigned short*)(ws + 16777216);    //  8 MB
  unsigned short* k_ws  = (unsigned short*)(ws + 25165824);    //  8 MB
  unsigned short* vT_ws = (unsigned short*)(ws + 33554432);    //  8 MB
  unsigned short* a_ws  = (unsigned short*)(ws + 41943040);    //  8 MB

  hipLaunchKernelGGL(k_cvt, dim3(4096), dim3(256), 0, stream, x, x_bf, 4194304 / 4);
  hipLaunchKernelGGL(k_tcvt, dim3(48, 16), dim3(256), 0, stream, w_attn, waT, 1024, 3072);
  hipLaunchKernelGGL(k_tcvt, dim3(16, 16), dim3(256), 0, stream, w_proj, wpT, 1024, 1024);
  hipLaunchKernelGGL(k_gemm_qkv, dim3(768), dim3(256), 0, stream,
                     x_bf, waT, b_attn, out, q_ws, k_ws, vT_ws);
  hipLaunchKernelGGL(k_attn, dim3(512), dim3(512), 0, stream, q_ws, k_ws, vT_ws, a_ws);
  hipLaunchKernelGGL(k_gemm_proj, dim3(256), dim3(256), 0, stream, a_ws, wpT, b_proj, out);
}

// Round 7
// 128.671 us; speedup vs baseline: 1.5242x; 1.5242x over previous
//
#include <hip/hip_runtime.h>
#include <stdint.h>

// Problem dims (fixed): B=2, S=2048, D=1024, H=16, d_head=64
#define SEQ 2048
#define A_SIZE 4194304   // 2*2048*1024 floats (output 'a'), present follows

typedef short short8 __attribute__((ext_vector_type(8)));
typedef float f32x4 __attribute__((ext_vector_type(4)));

#define AS1 __attribute__((address_space(1)))
#define AS3 __attribute__((address_space(3)))

static __device__ __forceinline__ void async16(const void* g, void* l) {
  __builtin_amdgcn_global_load_lds((const AS1 uint32_t*)g, (AS3 uint32_t*)l, 16, 0, 0);
}

static __device__ __forceinline__ unsigned short f2bf(float f) {
  union { float f; uint32_t u; } v; v.f = f;
  uint32_t u = v.u;
  return (unsigned short)((u + 0x7FFFu + ((u >> 16) & 1u)) >> 16);
}

static __device__ __forceinline__ uint32_t fbits(float f) {
  union { float f; uint32_t u; } v; v.f = f;
  return v.u;
}

// pack two floats to two truncated bf16 in one u32: low=p0, high=p1
static __device__ __forceinline__ uint32_t pack_bf2(float p0, float p1) {
  return __builtin_amdgcn_perm(fbits(p1), fbits(p0), 0x07060302u);
}

// ---------------- convert x -> bf16 (straight) ----------------
__global__ void k_cvt(const float* __restrict__ in, unsigned short* __restrict__ out, int n4) {
  int i = blockIdx.x * blockDim.x + threadIdx.x;
  if (i >= n4) return;
  float4 f = ((const float4*)in)[i];
  ushort4 o;
  o.x = f2bf(f.x); o.y = f2bf(f.y); o.z = f2bf(f.z); o.w = f2bf(f.w);
  ((ushort4*)out)[i] = o;
}

// ------- convert + transpose: in [R][C] f32 -> out [C][R] bf16 -------
__global__ void k_tcvt(const float* __restrict__ in, unsigned short* __restrict__ out,
                       int R, int C) {
  __shared__ unsigned short tile[64][65];
  int c0 = blockIdx.x * 64, r0 = blockIdx.y * 64;
  int tid = threadIdx.x;
  #pragma unroll
  for (int it = 0; it < 16; ++it) {
    int idx = it * 256 + tid;
    int r = idx >> 6, c = idx & 63;
    tile[r][c] = f2bf(in[(size_t)(r0 + r) * C + c0 + c]);
  }
  __syncthreads();
  #pragma unroll
  for (int it = 0; it < 16; ++it) {
    int idx = it * 256 + tid;
    int r = idx >> 6, c = idx & 63;
    out[(size_t)(c0 + r) * R + r0 + c] = tile[c][r];
  }
}

// ---------------- QKV GEMM: C[4096,3072] = A[4096,1024] * BT[3072,1024]^T + bias ----
// Epilogue writes K and V in MFMA-fragment-packed per-tile layouts:
//   kp[bh][tile][j=st*2+h][lane][8]  holds K[key][d(g,h)*8..+7], key=tile*64+(st>>1)*32+(st&1)*4+pr(qi)
//   vp[bh][tile][j=dt*2+half][lane][8] holds V^T[d=dt*16+qi][keys half*32+g*8..+7]
// so every attention load is a contiguous 1KB wave burst (lane*16B).
__global__ __launch_bounds__(256) void k_gemm_qkv(
    const unsigned short* __restrict__ A,
    const unsigned short* __restrict__ BT,
    const float* __restrict__ bias,
    float* __restrict__ outp,          // d_out base; present at +A_SIZE
    unsigned short* __restrict__ q_ws,
    unsigned short* __restrict__ kp,
    unsigned short* __restrict__ vp) {
  const int K = 1024;
  __shared__ unsigned short Asm[128 * 32];
  __shared__ unsigned short Bsm[128 * 32];
  int tid = threadIdx.x;
  int lane = tid & 63, w = tid >> 6;
  int g = lane >> 4, qi = lane & 15;
  int wr = w >> 1, wc = w & 1;
  int bm = blockIdx.x & 31, bn = blockIdx.x >> 5;
  const unsigned short* Ag = A + (size_t)bm * 128 * K;
  const unsigned short* Bg = BT + (size_t)bn * 128 * K;
  f32x4 acc[4][4] = {};
  for (int kt = 0; kt < K; kt += 32) {
    #pragma unroll
    for (int i = 0; i < 2; ++i) {
      int j = i * 256 + tid;
      async16(Ag + (size_t)(j >> 2) * K + kt + (j & 3) * 8,
              (char*)Asm + (i * 256 + w * 64) * 16);
      async16(Bg + (size_t)(j >> 2) * K + kt + (j & 3) * 8,
              (char*)Bsm + (i * 256 + w * 64) * 16);
    }
    __syncthreads();
    short8 af[4], bf[4];
    #pragma unroll
    for (int mi = 0; mi < 4; ++mi)
      af[mi] = *(const short8*)&Asm[(wr * 64 + mi * 16 + qi) * 32 + g * 8];
    #pragma unroll
    for (int ni = 0; ni < 4; ++ni)
      bf[ni] = *(const short8*)&Bsm[(wc * 64 + ni * 16 + qi) * 32 + g * 8];
    #pragma unroll
    for (int mi = 0; mi < 4; ++mi)
      #pragma unroll
      for (int ni = 0; ni < 4; ++ni)
        acc[mi][ni] = __builtin_amdgcn_mfma_f32_16x16x32_bf16(af[mi], bf[ni], acc[mi][ni], 0, 0, 0);
    __syncthreads();
  }
  // Epilogue: q (bf16 [B,H,S,d]), k/v fragment-packed, present (fp32).
  int m_base = bm * 128 + wr * 64;
  int n_base = bn * 128 + wc * 64;
  #pragma unroll
  for (int ni = 0; ni < 4; ++ni) {
    int n = n_base + ni * 16 + qi;
    float bv = bias[n];
    int which = n >> 10;
    int h = (n & 1023) >> 6, d = n & 63;
    #pragma unroll
    for (int mi = 0; mi < 4; ++mi) {
      #pragma unroll
      for (int r = 0; r < 4; ++r) {
        int m = m_base + mi * 16 + g * 4 + r;
        float val = acc[mi][ni][r] + bv;
        int b = m >> 11, s = m & 2047;
        if (which == 0) {
          q_ws[(((size_t)(b * 16 + h)) * SEQ + s) * 64 + d] = f2bf(val);
        } else if (which == 1) {
          outp[A_SIZE + (((size_t)(b * 32 + h)) * SEQ + s) * 64 + d] = val;      // present[b][0][h]
          int ks = s & 63;
          int st = ((ks >> 5) << 1) | ((ks >> 2) & 1);
          int qik = (((ks >> 3) & 3) << 2) | (ks & 3);
          int jK = st * 2 + (d >> 5);
          int laneK = ((d >> 3) & 3) * 16 + qik;
          kp[((((size_t)(b * 16 + h)) * 32 + (s >> 6)) * 8 + jK) * 512 + laneK * 8 + (d & 7)] = f2bf(val);
        } else {
          outp[A_SIZE + (((size_t)(b * 32 + 16 + h)) * SEQ + s) * 64 + d] = val; // present[b][1][h]
          int ks = s & 63;
          int jV = (d >> 4) * 2 + (ks >> 5);
          int laneV = ((ks >> 3) & 3) * 16 + (d & 15);
          vp[((((size_t)(b * 16 + h)) * 32 + (s >> 6)) * 8 + jV) * 512 + laneV * 8 + (ks & 7)] = f2bf(val);
        }
      }
    }
  }
}

// ---------------- proj GEMM: out[4096,1024] = A[4096,1024] * BT[1024,1024]^T + bias ----
__global__ __launch_bounds__(256) void k_gemm_proj(
    const unsigned short* __restrict__ A,
    const unsigned short* __restrict__ BT,
    const float* __restrict__ bias,
    float* __restrict__ outp) {
  const int K = 1024;
  __shared__ unsigned short Asm[128 * 32];
  __shared__ unsigned short Bsm[128 * 32];
  int tid = threadIdx.x;
  int lane = tid & 63, w = tid >> 6;
  int g = lane >> 4, qi = lane & 15;
  int wr = w >> 1, wc = w & 1;
  int bm = blockIdx.x & 31, bn = blockIdx.x >> 5;
  const unsigned short* Ag = A + (size_t)bm * 128 * K;
  const unsigned short* Bg = BT + (size_t)bn * 128 * K;
  f32x4 acc[4][4] = {};
  for (int kt = 0; kt < K; kt += 32) {
    #pragma unroll
    for (int i = 0; i < 2; ++i) {
      int j = i * 256 + tid;
      async16(Ag + (size_t)(j >> 2) * K + kt + (j & 3) * 8,
              (char*)Asm + (i * 256 + w * 64) * 16);
      async16(Bg + (size_t)(j >> 2) * K + kt + (j & 3) * 8,
              (char*)Bsm + (i * 256 + w * 64) * 16);
    }
    __syncthreads();
    short8 af[4], bf[4];
    #pragma unroll
    for (int mi = 0; mi < 4; ++mi)
      af[mi] = *(const short8*)&Asm[(wr * 64 + mi * 16 + qi) * 32 + g * 8];
    #pragma unroll
    for (int ni = 0; ni < 4; ++ni)
      bf[ni] = *(const short8*)&Bsm[(wc * 64 + ni * 16 + qi) * 32 + g * 8];
    #pragma unroll
    for (int mi = 0; mi < 4; ++mi)
      #pragma unroll
      for (int ni = 0; ni < 4; ++ni)
        acc[mi][ni] = __builtin_amdgcn_mfma_f32_16x16x32_bf16(af[mi], bf[ni], acc[mi][ni], 0, 0, 0);
    __syncthreads();
  }
  int m_base = bm * 128 + wr * 64;
  int n_base = bn * 128 + wc * 64;
  #pragma unroll
  for (int ni = 0; ni < 4; ++ni) {
    int n = n_base + ni * 16 + qi;
    float bv = bias[n];
    #pragma unroll
    for (int mi = 0; mi < 4; ++mi)
      #pragma unroll
      for (int r = 0; r < 4; ++r) {
        int m = m_base + mi * 16 + g * 4 + r;
        outp[(size_t)m * 1024 + n] = acc[mi][ni][r] + bv;
      }
  }
}

// ---------------- flash attention (causal), packed-fragment loads ----------------
// All K/V loads are contiguous 1KB wave bursts from kp/vp. Register-resident P
// (fragment permutation baked into the pack layout), defer-max, heavy/light
// pairing, XCD head pinning. Uniform loop: nfull unmasked tiles + 1 masked tile.
#define CSC 0.18033688f   /* 0.125 * log2(e) */
__global__ __launch_bounds__(512, 4) void k_attn(
    const unsigned short* __restrict__ q_ws,
    const unsigned short* __restrict__ kp,
    const unsigned short* __restrict__ vp,
    unsigned short* __restrict__ a_out) {
  int bid = blockIdx.x;
  int xcd = bid & 7;
  int jb = bid >> 3;                 // 0..63
  int bh = xcd * 4 + (jb & 3);       // 4 heads per XCD -> K/V L2-resident
  int pairidx = jb >> 2;             // 0..15
  int tid = threadIdx.x, lane = tid & 63, w = tid >> 6;
  int g = lane >> 4, qi = lane & 15;
  int tilesel = w >> 2, wl = w & 3;
  int q0 = (tilesel ? pairidx : (31 - pairidx)) * 64;
  int qw = q0 + wl * 16;
  int qrow = qw + qi;
  const unsigned short* Qb = q_ws + (size_t)bh * SEQ * 64;
  const unsigned short* Kp = kp + (size_t)bh * SEQ * 64;   // 32 tiles * 4096 shorts
  const unsigned short* Vp = vp + (size_t)bh * SEQ * 64;

  short8 qf0 = *(const short8*)&Qb[(size_t)qrow * 64 + g * 8];
  short8 qf1 = *(const short8*)&Qb[(size_t)qrow * 64 + g * 8 + 32];

  f32x4 oacc[4] = {};
  float m2 = -1.0e30f, l_run = 0.f;   // per-lane partial sum over this lane's keys
  f32x4 z = {};
  int nfull = qw >> 6;

  for (int t = 0; t <= nfull; ++t) {
    const unsigned short* Kt = Kp + (size_t)t * 4096;
    const unsigned short* Vt = Vp + (size_t)t * 4096;
    // 16 contiguous 1KB wave loads
    short8 kf[4][2];
    #pragma unroll
    for (int st = 0; st < 4; ++st) {
      kf[st][0] = *(const short8*)&Kt[(st * 2 + 0) * 512 + lane * 8];
      kf[st][1] = *(const short8*)&Kt[(st * 2 + 1) * 512 + lane * 8];
    }
    short8 vf0[4], vf1[4];
    #pragma unroll
    for (int dt = 0; dt < 4; ++dt) {
      vf0[dt] = *(const short8*)&Vt[(dt * 2 + 0) * 512 + lane * 8];
      vf1[dt] = *(const short8*)&Vt[(dt * 2 + 1) * 512 + lane * 8];
    }
    f32x4 sa[4];
    #pragma unroll
    for (int st = 0; st < 4; ++st) {
      sa[st] = __builtin_amdgcn_mfma_f32_16x16x32_bf16(kf[st][0], qf0, z, 0, 0, 0);
      sa[st] = __builtin_amdgcn_mfma_f32_16x16x32_bf16(kf[st][1], qf1, sa[st], 0, 0, 0);
    }
    // lane (g,qi): sa[st][r] = score for q-row qrow, key t*64+(st>>1)*32+(st&1)*4+g*8+r
    float tm = -1.0e30f;
    if (t == nfull) {   // wave-uniform masked tail tile
      #pragma unroll
      for (int st = 0; st < 4; ++st)
        #pragma unroll
        for (int r = 0; r < 4; ++r) {
          int key = t * 64 + (st >> 1) * 32 + (st & 1) * 4 + g * 8 + r;
          float v = (key <= qrow) ? sa[st][r] * CSC : -1.0e30f;
          sa[st][r] = v;
          tm = fmaxf(tm, v);
        }
    } else {
      #pragma unroll
      for (int st = 0; st < 4; ++st)
        #pragma unroll
        for (int r = 0; r < 4; ++r) {
          sa[st][r] *= CSC;
          tm = fmaxf(tm, sa[st][r]);
        }
    }
    if (!__all(tm - m2 <= 4.0f)) {      // defer-max (partial-max bound suffices)
      tm = fmaxf(tm, __shfl_xor(tm, 16, 64));
      tm = fmaxf(tm, __shfl_xor(tm, 32, 64));
      float mn = fmaxf(m2, tm);
      float alpha = exp2f(m2 - mn);
      l_run *= alpha;
      #pragma unroll
      for (int dt = 0; dt < 4; ++dt)
        #pragma unroll
        for (int r = 0; r < 4; ++r) oacc[dt][r] *= alpha;
      m2 = mn;
    }
    float ps = 0.f;
    union { uint32_t u[4]; short8 s; } pb0, pb1;
    #pragma unroll
    for (int st = 0; st < 4; ++st) {
      float p0 = exp2f(sa[st][0] - m2);
      float p1 = exp2f(sa[st][1] - m2);
      float p2 = exp2f(sa[st][2] - m2);
      float p3 = exp2f(sa[st][3] - m2);
      ps += (p0 + p1) + (p2 + p3);
      uint32_t lo = pack_bf2(p0, p1), hi = pack_bf2(p2, p3);
      if (st < 2) { pb0.u[st * 2] = lo; pb0.u[st * 2 + 1] = hi; }
      else        { pb1.u[(st - 2) * 2] = lo; pb1.u[(st - 2) * 2 + 1] = hi; }
    }
    l_run += ps;
    #pragma unroll
    for (int dt = 0; dt < 4; ++dt) {
      oacc[dt] = __builtin_amdgcn_mfma_f32_16x16x32_bf16(vf0[dt], pb0.s, oacc[dt], 0, 0, 0);
      oacc[dt] = __builtin_amdgcn_mfma_f32_16x16x32_bf16(vf1[dt], pb1.s, oacc[dt], 0, 0, 0);
    }
  }

  // one-time l reduce across the 4 lane-groups of each q-row
  l_run += __shfl_xor(l_run, 16, 64);
  l_run += __shfl_xor(l_run, 32, 64);
  float inv = 1.0f / l_run;
  int b = bh >> 4, h = bh & 15;
  size_t rowbase = ((size_t)(b * SEQ + qw + qi)) * 1024 + h * 64;
  #pragma unroll
  for (int dt = 0; dt < 4; ++dt) {
    ushort4 o;
    o.x = f2bf(oacc[dt][0] * inv);
    o.y = f2bf(oacc[dt][1] * inv);
    o.z = f2bf(oacc[dt][2] * inv);
    o.w = f2bf(oacc[dt][3] * inv);
    *(ushort4*)&a_out[rowbase + dt * 16 + g * 4] = o;
  }
}

// ---------------- launch ----------------
extern "C" void kernel_launch(void* const* d_in, const int* in_sizes, int n_in,
                              void* d_out, int out_size, void* d_ws, size_t ws_size,
                              hipStream_t stream) {
  const float* x      = (const float*)d_in[0];
  const float* w_attn = (const float*)d_in[1];
  const float* b_attn = (const float*)d_in[2];
  const float* w_proj = (const float*)d_in[3];
  const float* b_proj = (const float*)d_in[4];
  float* out = (float*)d_out;
  char* ws = (char*)d_ws;
  // ws layout (48 MB total)
  unsigned short* x_bf = (unsigned short*)(ws);               //  8 MB
  unsigned short* waT  = (unsigned short*)(ws + 8388608);     //  6 MB
  unsigned short* wpT  = (unsigned short*)(ws + 14680064);    //  2 MB
  unsigned short* q_ws = (unsigned short*)(ws + 16777216);    //  8 MB
  unsigned short* kp   = (unsigned short*)(ws + 25165824);    //  8 MB (fragment-packed K)
  unsigned short* vp   = (unsigned short*)(ws + 33554432);    //  8 MB (fragment-packed V)
  unsigned short* a_ws = (unsigned short*)(ws + 41943040);    //  8 MB

  hipLaunchKernelGGL(k_cvt, dim3(4096), dim3(256), 0, stream, x, x_bf, 4194304 / 4);
  hipLaunchKernelGGL(k_tcvt, dim3(48, 16), dim3(256), 0, stream, w_attn, waT, 1024, 3072);
  hipLaunchKernelGGL(k_tcvt, dim3(16, 16), dim3(256), 0, stream, w_proj, wpT, 1024, 1024);
  hipLaunchKernelGGL(k_gemm_qkv, dim3(768), dim3(256), 0, stream,
                     x_bf, waT, b_attn, out, q_ws, kp, vp);
  hipLaunchKernelGGL(k_attn, dim3(512), dim3(512), 0, stream, q_ws, kp, vp, a_ws);
  hipLaunchKernelGGL(k_gemm_proj, dim3(256), dim3(256), 0, stream, a_ws, wpT, b_proj, out);
}

// Round 8
// 116.873 us; speedup vs baseline: 1.6781x; 1.1009x over previous
//
#include <hip/hip_runtime.h>
#include <stdint.h>

// Problem dims (fixed): B=2, S=2048, D=1024, H=16, d_head=64
#define SEQ 2048
#define A_SIZE 4194304   // 2*2048*1024 floats (output 'a'), present follows

typedef short short8 __attribute__((ext_vector_type(8)));
typedef float f32x4 __attribute__((ext_vector_type(4)));

#define AS1 __attribute__((address_space(1)))
#define AS3 __attribute__((address_space(3)))

static __device__ __forceinline__ void async16(const void* g, void* l) {
  __builtin_amdgcn_global_load_lds((const AS1 uint32_t*)g, (AS3 uint32_t*)l, 16, 0, 0);
}

static __device__ __forceinline__ unsigned short f2bf(float f) {
  union { float f; uint32_t u; } v; v.f = f;
  uint32_t u = v.u;
  return (unsigned short)((u + 0x7FFFu + ((u >> 16) & 1u)) >> 16);
}

static __device__ __forceinline__ uint32_t fbits(float f) {
  union { float f; uint32_t u; } v; v.f = f;
  return v.u;
}

static __device__ __forceinline__ float bf2f(unsigned short b) {
  union { uint32_t u; float f; } c; c.u = ((uint32_t)b) << 16;
  return c.f;
}

// pack two floats to two truncated bf16 in one u32 (used for P in attn only)
static __device__ __forceinline__ uint32_t pack_bf2(float p0, float p1) {
  return __builtin_amdgcn_perm(fbits(p1), fbits(p0), 0x07060302u);
}

// RNE pack for GEMM outputs
static __device__ __forceinline__ uint32_t pack_rne(float a, float b) {
  return (uint32_t)f2bf(a) | ((uint32_t)f2bf(b) << 16);
}

// ---------------- convert x -> bf16 (straight) ----------------
__global__ void k_cvt(const float* __restrict__ in, unsigned short* __restrict__ out, int n4) {
  int i = blockIdx.x * blockDim.x + threadIdx.x;
  if (i >= n4) return;
  float4 f = ((const float4*)in)[i];
  ushort4 o;
  o.x = f2bf(f.x); o.y = f2bf(f.y); o.z = f2bf(f.z); o.w = f2bf(f.w);
  ((ushort4*)out)[i] = o;
}

// ------- convert + transpose: in [R][C] f32 -> out [C][R] bf16 -------
__global__ void k_tcvt(const float* __restrict__ in, unsigned short* __restrict__ out,
                       int R, int C) {
  __shared__ unsigned short tile[64][65];
  int c0 = blockIdx.x * 64, r0 = blockIdx.y * 64;
  int tid = threadIdx.x;
  #pragma unroll
  for (int it = 0; it < 16; ++it) {
    int idx = it * 256 + tid;
    int r = idx >> 6, c = idx & 63;
    tile[r][c] = f2bf(in[(size_t)(r0 + r) * C + c0 + c]);
  }
  __syncthreads();
  #pragma unroll
  for (int it = 0; it < 16; ++it) {
    int idx = it * 256 + tid;
    int r = idx >> 6, c = idx & 63;
    out[(size_t)(c0 + r) * R + r0 + c] = tile[c][r];
  }
}

// ---------------- QKV GEMM: C[4096,3072] = A[4096,1024] * BT[3072,1024]^T + bias ----
// K-loop: XOR-swizzled staging (slot' = slot ^ ((row>>1)&3)) -> 2-way (free) LDS reads.
// Epilogue: stage bias-added C col-major in LDS (T[n][m], stride 136), then emit
// fully 16B-coalesced stores: q row-major, kp/vp fragment-packed, present fp32.
__global__ __launch_bounds__(256) void k_gemm_qkv(
    const unsigned short* __restrict__ A,
    const unsigned short* __restrict__ BT,
    const float* __restrict__ bias,
    float* __restrict__ outp,          // d_out base; present at +A_SIZE
    unsigned short* __restrict__ q_ws,
    unsigned short* __restrict__ kp,
    unsigned short* __restrict__ vp) {
  const int K = 1024;
  __shared__ unsigned short Asm[128 * 32];
  __shared__ unsigned short Bsm[128 * 32];
  __shared__ unsigned short T[128 * 136];
  int tid = threadIdx.x;
  int lane = tid & 63, w = tid >> 6;
  int g = lane >> 4, qi = lane & 15;
  int wr = w >> 1, wc = w & 1;
  int bm = blockIdx.x & 31, bn = blockIdx.x >> 5;
  const unsigned short* Ag = A + (size_t)bm * 128 * K;
  const unsigned short* Bg = BT + (size_t)bn * 128 * K;
  int sw = (qi >> 1) & 3;
  f32x4 acc[4][4] = {};
  for (int kt = 0; kt < K; kt += 32) {
    #pragma unroll
    for (int i = 0; i < 2; ++i) {
      int j = i * 256 + tid;
      int cg = (j & 3) ^ ((j >> 3) & 3);          // pre-swizzled source chunk
      async16(Ag + (size_t)(j >> 2) * K + kt + cg * 8,
              (char*)Asm + (i * 256 + w * 64) * 16);
      async16(Bg + (size_t)(j >> 2) * K + kt + cg * 8,
              (char*)Bsm + (i * 256 + w * 64) * 16);
    }
    __syncthreads();
    short8 af[4], bf[4];
    #pragma unroll
    for (int mi = 0; mi < 4; ++mi)
      af[mi] = *(const short8*)&Asm[(wr * 64 + mi * 16 + qi) * 32 + (g ^ sw) * 8];
    #pragma unroll
    for (int ni = 0; ni < 4; ++ni)
      bf[ni] = *(const short8*)&Bsm[(wc * 64 + ni * 16 + qi) * 32 + (g ^ sw) * 8];
    #pragma unroll
    for (int mi = 0; mi < 4; ++mi)
      #pragma unroll
      for (int ni = 0; ni < 4; ++ni)
        acc[mi][ni] = __builtin_amdgcn_mfma_f32_16x16x32_bf16(af[mi], bf[ni], acc[mi][ni], 0, 0, 0);
    __syncthreads();
  }
  // ---- stage C col-major: T[n][m] (n = local col, m = local row) ----
  {
    int n0l = wc * 64, m0l = wr * 64;
    #pragma unroll
    for (int ni = 0; ni < 4; ++ni) {
      int nl = n0l + ni * 16 + qi;
      float bv = bias[bn * 128 + nl];
      #pragma unroll
      for (int mi = 0; mi < 4; ++mi) {
        int ml = m0l + mi * 16 + g * 4;
        uint2 pk;
        pk.x = pack_rne(acc[mi][ni][0] + bv, acc[mi][ni][1] + bv);
        pk.y = pack_rne(acc[mi][ni][2] + bv, acc[mi][ni][3] + bv);
        *(uint2*)&T[nl * 136 + ml] = pk;
      }
    }
  }
  __syncthreads();
  // ---- coalesced emit ----
  int third = bn >> 3;
  int b = bm >> 4;
  int s_base = (bm & 15) * 128;
  if (third == 0) {
    #pragma unroll
    for (int it = 0; it < 8; ++it) {
      int idx = it * 256 + tid;
      int sl = idx >> 4, d0 = idx & 15;
      unsigned short vv[8];
      #pragma unroll
      for (int jj = 0; jj < 8; ++jj) vv[jj] = T[(d0 * 8 + jj) * 136 + sl];
      int h = bn * 2 + (d0 >> 3);
      int din = (d0 & 7) * 8;
      *(short8*)&q_ws[(((size_t)(b * 16 + h)) * SEQ + s_base + sl) * 64 + din] = *(short8*)vv;
    }
  } else if (third == 1) {
    #pragma unroll
    for (int it = 0; it < 8; ++it) {
      int idx = it * 256 + tid;
      int sl = idx >> 4, d0 = idx & 15;
      unsigned short vv[8];
      #pragma unroll
      for (int jj = 0; jj < 8; ++jj) vv[jj] = T[(d0 * 8 + jj) * 136 + sl];
      int h = (bn - 8) * 2 + (d0 >> 3);
      int din = (d0 & 7) * 8;
      int sg = s_base + sl;
      // present[b][0][h] (fp32)
      float* pb = &outp[A_SIZE + ((((size_t)(b * 32 + h)) * SEQ + sg) * 64 + din)];
      float4 f0, f1;
      f0.x = bf2f(vv[0]); f0.y = bf2f(vv[1]); f0.z = bf2f(vv[2]); f0.w = bf2f(vv[3]);
      f1.x = bf2f(vv[4]); f1.y = bf2f(vv[5]); f1.z = bf2f(vv[6]); f1.w = bf2f(vv[7]);
      *(float4*)&pb[0] = f0;
      *(float4*)&pb[4] = f1;
      // kp fragment-packed
      int ks = sg & 63, tile = sg >> 6;
      int st = ((ks >> 5) << 1) | ((ks >> 2) & 1);
      int qik = (((ks >> 3) & 3) << 2) | (ks & 3);
      int jK = st * 2 + (din >> 5);
      int laneK = ((din >> 3) & 3) * 16 + qik;
      *(short8*)&kp[((((size_t)(b * 16 + h)) * 32 + tile) * 8 + jK) * 512 + laneK * 8] = *(short8*)vv;
    }
  } else {
    // vp: contiguous b128 LDS reads (key-runs) -> 16B stores
    #pragma unroll
    for (int it = 0; it < 8; ++it) {
      int idx = it * 256 + tid;
      int dcol = idx >> 4, k8 = idx & 15;
      short8 vv = *(const short8*)&T[dcol * 136 + k8 * 8];
      int h = (bn - 16) * 2 + (dcol >> 6);
      int d = dcol & 63;
      int sg = s_base + k8 * 8;
      int tile = sg >> 6, ks0 = sg & 63;
      int jV = (d >> 4) * 2 + (ks0 >> 5);
      int laneV = ((ks0 >> 3) & 3) * 16 + (d & 15);
      *(short8*)&vp[((((size_t)(b * 16 + h)) * 32 + tile) * 8 + jV) * 512 + laneV * 8] = vv;
    }
    // present[b][1][h] (fp32)
    #pragma unroll
    for (int it = 0; it < 8; ++it) {
      int idx = it * 256 + tid;
      int sl = idx >> 4, d0 = idx & 15;
      unsigned short vv[8];
      #pragma unroll
      for (int jj = 0; jj < 8; ++jj) vv[jj] = T[(d0 * 8 + jj) * 136 + sl];
      int h = (bn - 16) * 2 + (d0 >> 3);
      int din = (d0 & 7) * 8;
      int sg = s_base + sl;
      float* pb = &outp[A_SIZE + ((((size_t)(b * 32 + 16 + h)) * SEQ + sg) * 64 + din)];
      float4 f0, f1;
      f0.x = bf2f(vv[0]); f0.y = bf2f(vv[1]); f0.z = bf2f(vv[2]); f0.w = bf2f(vv[3]);
      f1.x = bf2f(vv[4]); f1.y = bf2f(vv[5]); f1.z = bf2f(vv[6]); f1.w = bf2f(vv[7]);
      *(float4*)&pb[0] = f0;
      *(float4*)&pb[4] = f1;
    }
  }
}

// ---------------- proj GEMM: out[4096,1024] = A[4096,1024] * BT[1024,1024]^T + bias ----
__global__ __launch_bounds__(256) void k_gemm_proj(
    const unsigned short* __restrict__ A,
    const unsigned short* __restrict__ BT,
    const float* __restrict__ bias,
    float* __restrict__ outp) {
  const int K = 1024;
  __shared__ unsigned short Asm[128 * 32];
  __shared__ unsigned short Bsm[128 * 32];
  int tid = threadIdx.x;
  int lane = tid & 63, w = tid >> 6;
  int g = lane >> 4, qi = lane & 15;
  int wr = w >> 1, wc = w & 1;
  int bm = blockIdx.x & 31, bn = blockIdx.x >> 5;
  const unsigned short* Ag = A + (size_t)bm * 128 * K;
  const unsigned short* Bg = BT + (size_t)bn * 128 * K;
  int sw = (qi >> 1) & 3;
  f32x4 acc[4][4] = {};
  for (int kt = 0; kt < K; kt += 32) {
    #pragma unroll
    for (int i = 0; i < 2; ++i) {
      int j = i * 256 + tid;
      int cg = (j & 3) ^ ((j >> 3) & 3);
      async16(Ag + (size_t)(j >> 2) * K + kt + cg * 8,
              (char*)Asm + (i * 256 + w * 64) * 16);
      async16(Bg + (size_t)(j >> 2) * K + kt + cg * 8,
              (char*)Bsm + (i * 256 + w * 64) * 16);
    }
    __syncthreads();
    short8 af[4], bf[4];
    #pragma unroll
    for (int mi = 0; mi < 4; ++mi)
      af[mi] = *(const short8*)&Asm[(wr * 64 + mi * 16 + qi) * 32 + (g ^ sw) * 8];
    #pragma unroll
    for (int ni = 0; ni < 4; ++ni)
      bf[ni] = *(const short8*)&Bsm[(wc * 64 + ni * 16 + qi) * 32 + (g ^ sw) * 8];
    #pragma unroll
    for (int mi = 0; mi < 4; ++mi)
      #pragma unroll
      for (int ni = 0; ni < 4; ++ni)
        acc[mi][ni] = __builtin_amdgcn_mfma_f32_16x16x32_bf16(af[mi], bf[ni], acc[mi][ni], 0, 0, 0);
    __syncthreads();
  }
  int m_base = bm * 128 + wr * 64;
  int n_base = bn * 128 + wc * 64;
  #pragma unroll
  for (int ni = 0; ni < 4; ++ni) {
    int n = n_base + ni * 16 + qi;
    float bv = bias[n];
    #pragma unroll
    for (int mi = 0; mi < 4; ++mi)
      #pragma unroll
      for (int r = 0; r < 4; ++r) {
        int m = m_base + mi * 16 + g * 4 + r;
        outp[(size_t)m * 1024 + n] = acc[mi][ni][r] + bv;
      }
  }
}

// ---------------- flash attention (causal), packed-fragment loads ----------------
#define CSC 0.18033688f   /* 0.125 * log2(e) */
__global__ __launch_bounds__(512, 4) void k_attn(
    const unsigned short* __restrict__ q_ws,
    const unsigned short* __restrict__ kp,
    const unsigned short* __restrict__ vp,
    unsigned short* __restrict__ a_out) {
  int bid = blockIdx.x;
  int xcd = bid & 7;
  int jb = bid >> 3;                 // 0..63
  int bh = xcd * 4 + (jb & 3);       // 4 heads per XCD -> K/V L2-resident
  int pairidx = jb >> 2;             // 0..15
  int tid = threadIdx.x, lane = tid & 63, w = tid >> 6;
  int g = lane >> 4, qi = lane & 15;
  int tilesel = w >> 2, wl = w & 3;
  int q0 = (tilesel ? pairidx : (31 - pairidx)) * 64;
  int qw = q0 + wl * 16;
  int qrow = qw + qi;
  const unsigned short* Qb = q_ws + (size_t)bh * SEQ * 64;
  const unsigned short* Kp = kp + (size_t)bh * SEQ * 64;   // 32 tiles * 4096 shorts
  const unsigned short* Vp = vp + (size_t)bh * SEQ * 64;

  short8 qf0 = *(const short8*)&Qb[(size_t)qrow * 64 + g * 8];
  short8 qf1 = *(const short8*)&Qb[(size_t)qrow * 64 + g * 8 + 32];

  f32x4 oacc[4] = {};
  float m2 = -1.0e30f, l_run = 0.f;   // per-lane partial sum over this lane's keys
  f32x4 z = {};
  int nfull = qw >> 6;

  for (int t = 0; t <= nfull; ++t) {
    const unsigned short* Kt = Kp + (size_t)t * 4096;
    const unsigned short* Vt = Vp + (size_t)t * 4096;
    // 16 contiguous 1KB wave loads
    short8 kf[4][2];
    #pragma unroll
    for (int st = 0; st < 4; ++st) {
      kf[st][0] = *(const short8*)&Kt[(st * 2 + 0) * 512 + lane * 8];
      kf[st][1] = *(const short8*)&Kt[(st * 2 + 1) * 512 + lane * 8];
    }
    short8 vf0[4], vf1[4];
    #pragma unroll
    for (int dt = 0; dt < 4; ++dt) {
      vf0[dt] = *(const short8*)&Vt[(dt * 2 + 0) * 512 + lane * 8];
      vf1[dt] = *(const short8*)&Vt[(dt * 2 + 1) * 512 + lane * 8];
    }
    f32x4 sa[4];
    #pragma unroll
    for (int st = 0; st < 4; ++st) {
      sa[st] = __builtin_amdgcn_mfma_f32_16x16x32_bf16(kf[st][0], qf0, z, 0, 0, 0);
      sa[st] = __builtin_amdgcn_mfma_f32_16x16x32_bf16(kf[st][1], qf1, sa[st], 0, 0, 0);
    }
    // lane (g,qi): sa[st][r] = score for q-row qrow, key t*64+(st>>1)*32+(st&1)*4+g*8+r
    float tm = -1.0e30f;
    if (t == nfull) {   // wave-uniform masked tail tile
      #pragma unroll
      for (int st = 0; st < 4; ++st)
        #pragma unroll
        for (int r = 0; r < 4; ++r) {
          int key = t * 64 + (st >> 1) * 32 + (st & 1) * 4 + g * 8 + r;
          float v = (key <= qrow) ? sa[st][r] * CSC : -1.0e30f;
          sa[st][r] = v;
          tm = fmaxf(tm, v);
        }
    } else {
      #pragma unroll
      for (int st = 0; st < 4; ++st)
        #pragma unroll
        for (int r = 0; r < 4; ++r) {
          sa[st][r] *= CSC;
          tm = fmaxf(tm, sa[st][r]);
        }
    }
    if (!__all(tm - m2 <= 4.0f)) {      // defer-max (partial-max bound suffices)
      tm = fmaxf(tm, __shfl_xor(tm, 16, 64));
      tm = fmaxf(tm, __shfl_xor(tm, 32, 64));
      float mn = fmaxf(m2, tm);
      float alpha = exp2f(m2 - mn);
      l_run *= alpha;
      #pragma unroll
      for (int dt = 0; dt < 4; ++dt)
        #pragma unroll
        for (int r = 0; r < 4; ++r) oacc[dt][r] *= alpha;
      m2 = mn;
    }
    float ps = 0.f;
    union { uint32_t u[4]; short8 s; } pb0, pb1;
    #pragma unroll
    for (int st = 0; st < 4; ++st) {
      float p0 = exp2f(sa[st][0] - m2);
      float p1 = exp2f(sa[st][1] - m2);
      float p2 = exp2f(sa[st][2] - m2);
      float p3 = exp2f(sa[st][3] - m2);
      ps += (p0 + p1) + (p2 + p3);
      uint32_t lo = pack_bf2(p0, p1), hi = pack_bf2(p2, p3);
      if (st < 2) { pb0.u[st * 2] = lo; pb0.u[st * 2 + 1] = hi; }
      else        { pb1.u[(st - 2) * 2] = lo; pb1.u[(st - 2) * 2 + 1] = hi; }
    }
    l_run += ps;
    #pragma unroll
    for (int dt = 0; dt < 4; ++dt) {
      oacc[dt] = __builtin_amdgcn_mfma_f32_16x16x32_bf16(vf0[dt], pb0.s, oacc[dt], 0, 0, 0);
      oacc[dt] = __builtin_amdgcn_mfma_f32_16x16x32_bf16(vf1[dt], pb1.s, oacc[dt], 0, 0, 0);
    }
  }

  // one-time l reduce across the 4 lane-groups of each q-row
  l_run += __shfl_xor(l_run, 16, 64);
  l_run += __shfl_xor(l_run, 32, 64);
  float inv = 1.0f / l_run;
  int b = bh >> 4, h = bh & 15;
  size_t rowbase = ((size_t)(b * SEQ + qw + qi)) * 1024 + h * 64;
  #pragma unroll
  for (int dt = 0; dt < 4; ++dt) {
    ushort4 o;
    o.x = f2bf(oacc[dt][0] * inv);
    o.y = f2bf(oacc[dt][1] * inv);
    o.z = f2bf(oacc[dt][2] * inv);
    o.w = f2bf(oacc[dt][3] * inv);
    *(ushort4*)&a_out[rowbase + dt * 16 + g * 4] = o;
  }
}

// ---------------- launch ----------------
extern "C" void kernel_launch(void* const* d_in, const int* in_sizes, int n_in,
                              void* d_out, int out_size, void* d_ws, size_t ws_size,
                              hipStream_t stream) {
  const float* x      = (const float*)d_in[0];
  const float* w_attn = (const float*)d_in[1];
  const float* b_attn = (const float*)d_in[2];
  const float* w_proj = (const float*)d_in[3];
  const float* b_proj = (const float*)d_in[4];
  float* out = (float*)d_out;
  char* ws = (char*)d_ws;
  // ws layout (48 MB total)
  unsigned short* x_bf = (unsigned short*)(ws);               //  8 MB
  unsigned short* waT  = (unsigned short*)(ws + 8388608);     //  6 MB
  unsigned short* wpT  = (unsigned short*)(ws + 14680064);    //  2 MB
  unsigned short* q_ws = (unsigned short*)(ws + 16777216);    //  8 MB
  unsigned short* kp   = (unsigned short*)(ws + 25165824);    //  8 MB (fragment-packed K)
  unsigned short* vp   = (unsigned short*)(ws + 33554432);    //  8 MB (fragment-packed V)
  unsigned short* a_ws = (unsigned short*)(ws + 41943040);    //  8 MB

  hipLaunchKernelGGL(k_cvt, dim3(4096), dim3(256), 0, stream, x, x_bf, 4194304 / 4);
  hipLaunchKernelGGL(k_tcvt, dim3(48, 16), dim3(256), 0, stream, w_attn, waT, 1024, 3072);
  hipLaunchKernelGGL(k_tcvt, dim3(16, 16), dim3(256), 0, stream, w_proj, wpT, 1024, 1024);
  hipLaunchKernelGGL(k_gemm_qkv, dim3(768), dim3(256), 0, stream,
                     x_bf, waT, b_attn, out, q_ws, kp, vp);
  hipLaunchKernelGGL(k_attn, dim3(512), dim3(512), 0, stream, q_ws, kp, vp, a_ws);
  hipLaunchKernelGGL(k_gemm_proj, dim3(256), dim3(256), 0, stream, a_ws, wpT, b_proj, out);
}